// Round 2
// baseline (417.639 us; speedup 1.0000x reference)
//
#include <hip/hip_runtime.h>

typedef float f32x4 __attribute__((ext_vector_type(4)));
typedef float f32x16 __attribute__((ext_vector_type(16)));
typedef __bf16 bf16x8 __attribute__((ext_vector_type(8)));

__device__ __forceinline__ unsigned short f2bf(float f) {
  unsigned int u = __float_as_uint(f);
  u = (u + 0x7FFFu + ((u >> 16) & 1u)) >> 16;
  return (unsigned short)u;
}
__device__ __forceinline__ float bf2f(unsigned short u) {
  return __uint_as_float((unsigned int)u << 16);
}

__device__ __forceinline__ f32x4 mfma16(bf16x8 a, bf16x8 b, f32x4 c) {
  return __builtin_amdgcn_mfma_f32_16x16x32_bf16(a, b, c, 0, 0, 0);
}
__device__ __forceinline__ f32x16 mfma32(bf16x8 a, bf16x8 b, f32x16 c) {
  return __builtin_amdgcn_mfma_f32_32x32x16_bf16(a, b, c, 0, 0, 0);
}

// packed f32->bf16 pair (RNE), lo = a, hi = b
__device__ __forceinline__ unsigned int cvtpk_bf16(float a, float b) {
  unsigned int r;
  asm("v_cvt_pk_bf16_f32 %0, %1, %2" : "=v"(r) : "v"(a), "v"(b));
  return r;
}
// swap upper 32 lanes of a with lower 32 lanes of b (both outputs used)
__device__ __forceinline__ void pl32swap(unsigned int& a, unsigned int& b) {
  asm("v_permlane32_swap_b32 %0, %1" : "+v"(a), "+v"(b));
}

__device__ __forceinline__ void load8_bf16(const unsigned short* p, unsigned short* d) {
  *(uint4*)d = *(const uint4*)p;
}
__device__ __forceinline__ void load8_bf16(const float* p, unsigned short* d) {
  float4 a = *(const float4*)p;
  float4 b = *(const float4*)(p + 4);
  __align__(16) unsigned short t[8] = {f2bf(a.x), f2bf(a.y), f2bf(a.z), f2bf(a.w),
                                       f2bf(b.x), f2bf(b.y), f2bf(b.z), f2bf(b.w)};
  *(uint4*)d = *(uint4*)t;
}

// Async global->LDS 16B DMA. LDS dest must be wave-uniform base + lane*16.
__device__ __forceinline__ void gload_lds16(const unsigned short* g, unsigned short* l) {
  __builtin_amdgcn_global_load_lds(
      (const __attribute__((address_space(1))) void*)g,
      (__attribute__((address_space(3))) void*)l, 16, 0, 0);
}

// fp32 -> bf16, 8 elems/thread.
__global__ __launch_bounds__(256) void convert_gen(const float* __restrict__ src,
                                                   unsigned short* __restrict__ dst) {
  int idx = (blockIdx.x * 256 + threadIdx.x) * 8;
  __align__(16) unsigned short t[8];
  load8_bf16(src + idx, t);
  *(uint4*)(dst + idx) = *(uint4*)t;
}

// W1|W2|W3 (each 1M fp32) -> contiguous bf16. 1536 blocks.
__global__ __launch_bounds__(256) void convert_w3(const float* __restrict__ W1,
                                                  const float* __restrict__ W2,
                                                  const float* __restrict__ W3,
                                                  unsigned short* __restrict__ dst) {
  int i = blockIdx.x;
  int sel = i >> 9;
  const float* src = (sel == 0) ? W1 : (sel == 1) ? W2 : W3;
  int off = (i & 511) * 2048 + threadIdx.x * 8;
  __align__(16) unsigned short t[8];
  load8_bf16(src + off, t);
  *(uint4*)(dst + sel * 1048576 + off) = *(uint4*)t;
}

// Fused QKV projection, all-bf16, global_load_lds staging, unpadded LDS.
__global__ __launch_bounds__(256) void gemm_qkv(const unsigned short* __restrict__ A,
                                                const unsigned short* __restrict__ WB,
                                                unsigned short* __restrict__ q,
                                                unsigned short* __restrict__ k,
                                                unsigned short* __restrict__ v) {
  __shared__ __align__(16) unsigned short As[128][32];
  __shared__ __align__(16) unsigned short Bs[128][32];
  const int t = threadIdx.x;
  const int lane = t & 63;
  const int wid = t >> 6;
  const int quad = lane >> 4;
  const int l16 = lane & 15;
  const int wm = (wid >> 1) << 6;
  const int wn = (wid & 1) << 6;
  const int sel = blockIdx.x >> 3;
  const int nb = (blockIdx.x & 7) << 7;
  const int mbase = blockIdx.y * 128;
  const unsigned short* Bt = WB + sel * 1048576;
  unsigned short* C = (sel == 0) ? q : (sel == 1) ? k : v;

  f32x4 acc[4][4] = {};

  for (int k0 = 0; k0 < 1024; k0 += 32) {
#pragma unroll
    for (int i = 0; i < 2; ++i) {
      int c = t + (i << 8);
      int row = c >> 2;
      int col = (c & 3) << 3;
      gload_lds16(A + (size_t)(mbase + row) * 1024 + k0 + col, &As[row][col]);
      gload_lds16(Bt + (size_t)(nb + row) * 1024 + k0 + col, &Bs[row][col]);
    }
    __syncthreads();
    bf16x8 af[4], bfr[4];
#pragma unroll
    for (int mt = 0; mt < 4; ++mt)
      af[mt] = *(const bf16x8*)(&As[wm + mt * 16 + l16][quad * 8]);
#pragma unroll
    for (int nt = 0; nt < 4; ++nt)
      bfr[nt] = *(const bf16x8*)(&Bs[wn + nt * 16 + l16][quad * 8]);
#pragma unroll
    for (int mt = 0; mt < 4; ++mt)
#pragma unroll
      for (int nt = 0; nt < 4; ++nt)
        acc[mt][nt] = mfma16(af[mt], bfr[nt], acc[mt][nt]);
    __syncthreads();
  }

  const bool rope = (sel < 2);
#pragma unroll
  for (int mt = 0; mt < 4; ++mt) {
#pragma unroll
    for (int nt = 0; nt < 4; ++nt) {
#pragma unroll
      for (int r = 0; r < 4; ++r) {
        int row_g = mbase + wm + mt * 16 + quad * 4 + r;
        int col_g = nb + wn + nt * 16 + l16;
        float val = acc[mt][nt][r];
        if (rope) {  // interleaved RoPE; partner col = col^1 lives in lane^1
          float other = __shfl_xor(val, 1);
          int s = (((row_g & 2047) << 3) + (col_g >> 7)) & 2047;  // view-seq position
          int d = col_g & 127;
          float invf = __expf(-0.14391156f * (float)(d >> 1));  // ln(1e4)/64
          float ang = (float)s * invf;
          float sv, cv;
          __sincosf(ang, &sv, &cv);
          val = (d & 1) ? (val * cv + other * sv) : (val * cv - other * sv);
        }
        C[(size_t)row_g * 1024 + col_g] = f2bf(val);
      }
    }
  }
}

// Plain per-bh transpose: vT[bh][d][s] = v[bh][s][d].
__global__ __launch_bounds__(256) void transpose_v(const unsigned short* __restrict__ Vn,
                                                   unsigned short* __restrict__ VT) {
  __shared__ __align__(16) unsigned short tile[64][72];
  const int t = threadIdx.x;
  const int s0 = blockIdx.x * 64;
  const int d0 = blockIdx.y * 64;
  const int bh = blockIdx.z;
  const size_t base = (size_t)bh * (2048 * 128);
#pragma unroll
  for (int i = 0; i < 2; ++i) {
    int c = t + (i << 8);
    int sr = c >> 3;
    int dc = (c & 7) << 3;
    *(uint4*)(&tile[sr][dc]) = *(const uint4*)(Vn + base + (size_t)(s0 + sr) * 128 + d0 + dc);
  }
  __syncthreads();
#pragma unroll
  for (int i = 0; i < 2; ++i) {
    int c = t + (i << 8);
    int dr = c >> 3;
    int sc = (c & 7) << 3;
    __align__(16) unsigned short tmp[8];
#pragma unroll
    for (int j = 0; j < 8; ++j) tmp[j] = tile[sc + j][dr];
    *(uint4*)(VT + base + (size_t)(d0 + dr) * 2048 + s0 + sc) = *(uint4*)tmp;
  }
}

// Final projection: A rows remap RowLinear pre-shuffle onto oT[bh][d][s].
__global__ __launch_bounds__(256) void gemm_out(const unsigned short* __restrict__ OT,
                                                const unsigned short* __restrict__ Bt,
                                                float* __restrict__ C) {
  __shared__ __align__(16) char smem_raw[128 * 68 * 4];  // Ts epilogue needs 34816 B
  auto As = (unsigned short(*)[32])smem_raw;
  auto Bs = (unsigned short(*)[32])(smem_raw + 128 * 32 * 2);
  const int t = threadIdx.x;
  const int lane = t & 63;
  const int wid = t >> 6;
  const int quad = lane >> 4;
  const int l16 = lane & 15;
  const int wm = (wid >> 1) << 6;
  const int wn = (wid & 1) << 6;
  const int mbase = blockIdx.y * 128;
  const int nbase = blockIdx.x * 128;

  f32x4 acc[4][4] = {};

  for (int k0 = 0; k0 < 1024; k0 += 32) {
#pragma unroll
    for (int i = 0; i < 2; ++i) {
      int c = t + (i << 8);
      int row = c >> 2;
      int col = (c & 3) << 3;
      int R = mbase + row;
      int b = R >> 11;
      int ii = R & 2047;
      const unsigned short* src = OT + (size_t)(b * 8 + (ii >> 8)) * (128 * 2048) +
                                  (size_t)((ii >> 1) & 127) * 2048 + ((ii & 1) << 10) +
                                  k0 + col;
      gload_lds16(src, &As[row][col]);
      gload_lds16(Bt + (size_t)(nbase + row) * 1024 + k0 + col, &Bs[row][col]);
    }
    __syncthreads();
    bf16x8 af[4], bfr[4];
#pragma unroll
    for (int mt = 0; mt < 4; ++mt)
      af[mt] = *(const bf16x8*)(&As[wm + mt * 16 + l16][quad * 8]);
#pragma unroll
    for (int nt = 0; nt < 4; ++nt)
      bfr[nt] = *(const bf16x8*)(&Bs[wn + nt * 16 + l16][quad * 8]);
#pragma unroll
    for (int mt = 0; mt < 4; ++mt)
#pragma unroll
      for (int nt = 0; nt < 4; ++nt)
        acc[mt][nt] = mfma16(af[mt], bfr[nt], acc[mt][nt]);
    __syncthreads();
  }

  // out[b][s2][e2], s2 = (row&1)*1024 + col, e2 = (row&2047)>>1.
  float(*Ts)[68] = (float(*)[68])smem_raw;
  const int b = mbase >> 11;
  const int ebase = (mbase & 2047) >> 1;
#pragma unroll
  for (int p = 0; p < 2; ++p) {
    __syncthreads();
#pragma unroll
    for (int mt = 0; mt < 4; ++mt)
#pragma unroll
      for (int nt = 0; nt < 4; ++nt)
#pragma unroll
        for (int rr = p; rr < 4; rr += 2) {
          int col_local = wn + nt * 16 + l16;
          int row_local = wm + mt * 16 + quad * 4 + rr;
          Ts[col_local][row_local >> 1] = acc[mt][nt][rr];
        }
    __syncthreads();
    int srow = t >> 1;
    int e0 = (t & 1) << 5;
    float* dst = C + (size_t)b * 2097152 +
                 (size_t)(p * 1024 + nbase + srow) * 1024 + ebase + e0;
#pragma unroll
    for (int j = 0; j < 8; ++j)
      ((float4*)dst)[j] = *(const float4*)&Ts[srow][e0 + j * 4];
  }
}

// Flash attention [BH=32, S=2048, D=128]; split-KV: each block does 1024 KV
// positions for BQ=128 (4 waves x 32 q-cols), BKV=64. Swapped QK^T on 32x32
// MFMA (S^T in regs, q = lane&31), in-register softmax, cvt_pk+permlane32
// P-repack, PV as V^T x P^T -> O^T. Single 32KB K+V LDS buffer staged via
// global_load_lds with PRE-SWIZZLED global source (linear LDS dest); 4
// blocks/CU. Writes per-half normalized partial O^T + (m,l).
__global__ __launch_bounds__(256, 4) void flash_attn(const unsigned short* __restrict__ Q,
                                                     const unsigned short* __restrict__ Kg,
                                                     const unsigned short* __restrict__ VTg,
                                                     unsigned short* __restrict__ PO0,
                                                     unsigned short* __restrict__ PO1,
                                                     float2* __restrict__ ML0,
                                                     float2* __restrict__ ML1) {
  __shared__ __align__(16) char sm[34816];  // K 16KB | V 16KB; epilogue To overlays
  const int t = threadIdx.x;
  const int lane = t & 63;
  const int wid = t >> 6;
  const int l31 = lane & 31;
  const int hi = lane >> 5;
  const int x16 = (l31 & 7) << 4;  // XOR swizzle key (byte units)
  const int i = blockIdx.x;        // [0,1024); i%32 -> bh (XCD-clustered)
  const int bh = (i & 7) + ((i >> 3) & 3) * 8;
  const int half = (i >> 5) & 1;
  const int qbase = (i >> 6) << 7;
  const int kv_lo = half << 10;
  const int kv_hi = kv_lo + 1024;
  const size_t base = (size_t)bh * (2048 * 128);
  const float scale = 0.3535533905932738f;  // 1/sqrt(H=8)

  unsigned short* PO = half ? PO1 : PO0;
  float2* ML = half ? ML1 : ML0;
  unsigned short* Ks_lin = (unsigned short*)sm;
  unsigned short* Vs_lin = (unsigned short*)(sm + 16384);

  // Q fragments (B-operand): j = q = l31, k-dim slice = hi*8 within each 16.
  bf16x8 qf[8];
  {
    const unsigned short* qp = Q + base + (size_t)(qbase + wid * 32 + l31) * 128 + hi * 8;
#pragma unroll
    for (int ks = 0; ks < 8; ++ks) qf[ks] = *(const bf16x8*)(qp + ks * 16);
  }

  f32x16 accO[4] = {};  // O^T: rows d, cols q = l31
  float m = -__builtin_inff();
  float l = 0.f;

  const unsigned short* Kg_b = Kg + base;
  const unsigned short* Vg_b = VTg + base;

  // prologue: DMA tile kv_lo (pre-swizzled source -> linear LDS dest)
#pragma unroll
  for (int j = 0; j < 4; ++j) {
    int c = t + (j << 8);
    int row = c >> 4, ch = c & 15;
    gload_lds16(Kg_b + (size_t)(kv_lo + row) * 128 + ((ch ^ (row & 7)) << 3),
                Ks_lin + c * 8);
    int d = c >> 3, cv = c & 7;
    gload_lds16(Vg_b + (size_t)d * 2048 + kv_lo + ((cv ^ (d & 7)) << 3),
                Vs_lin + c * 8);
  }
  __syncthreads();

  for (int kv = kv_lo; kv < kv_hi; kv += 64) {
    const char* Kb = sm;
    const char* Vb = sm + 16384;

    // QK^T swapped: S^T (rows k, cols q = l31)
    f32x16 s0 = {}, s1 = {};
#pragma unroll
    for (int ks = 0; ks < 8; ++ks) {
      int cb = (ks * 32 + hi * 16) ^ x16;
      bf16x8 k0 = *(const bf16x8*)(Kb + l31 * 256 + cb);
      bf16x8 k1 = *(const bf16x8*)(Kb + 8192 + l31 * 256 + cb);
      s0 = mfma32(k0, qf[ks], s0);
      s1 = mfma32(k1, qf[ks], s1);
    }

    // online softmax: per-lane row (q = l31); tree reductions
    float tm[16];
#pragma unroll
    for (int r = 0; r < 16; ++r) tm[r] = fmaxf(s0[r], s1[r]);
#pragma unroll
    for (int d = 8; d > 0; d >>= 1)
#pragma unroll
      for (int r = 0; r < d; ++r) tm[r] = fmaxf(tm[r], tm[r + d]);
    float mx = fmaxf(tm[0], __shfl_xor(tm[0], 32));
    if (__any(mx > m + 16.f)) {  // defer-max: P bounded by e^(16*scale)=287
      float mnew = fmaxf(m, mx);
      float alpha = __expf((m - mnew) * scale);
      l *= alpha;
#pragma unroll
      for (int dt = 0; dt < 4; ++dt)
#pragma unroll
        for (int r = 0; r < 16; ++r) accO[dt][r] *= alpha;
      m = mnew;
    }
    float negms = -m * scale;
#pragma unroll
    for (int r = 0; r < 16; ++r) s0[r] = __expf(fmaf(s0[r], scale, negms));
#pragma unroll
    for (int r = 0; r < 16; ++r) s1[r] = __expf(fmaf(s1[r], scale, negms));
    float ts[16];
#pragma unroll
    for (int r = 0; r < 16; ++r) ts[r] = s0[r] + s1[r];
#pragma unroll
    for (int d = 8; d > 0; d >>= 1)
#pragma unroll
      for (int r = 0; r < d; ++r) ts[r] += ts[r + d];
    l += ts[0] + __shfl_xor(ts[0], 32);

    // repack P^T -> B-fragments: cvt_pk pairs + permlane32_swap
    bf16x8 pfrag[4];
#pragma unroll
    for (int kb = 0; kb < 4; ++kb) {
      const f32x16& S = (kb < 2) ? s0 : s1;
      const int b = (kb & 1) * 8;
      unsigned int a0 = cvtpk_bf16(S[b + 0], S[b + 1]);
      unsigned int a1 = cvtpk_bf16(S[b + 2], S[b + 3]);
      unsigned int a2 = cvtpk_bf16(S[b + 4], S[b + 5]);
      unsigned int a3 = cvtpk_bf16(S[b + 6], S[b + 7]);
      pl32swap(a0, a2);
      pl32swap(a1, a3);
      union { unsigned int u[4]; bf16x8 v; } pu;
      pu.u[0] = a0; pu.u[1] = a1; pu.u[2] = a2; pu.u[3] = a3;
      pfrag[kb] = pu.v;
    }

    // PV: O^T[d][q] += V^T-frag (i=d) x P^T-frag (j=q)
#pragma unroll
    for (int dt = 0; dt < 4; ++dt) {
#pragma unroll
      for (int kb = 0; kb < 4; ++kb) {
        bf16x8 vfr = *(const bf16x8*)(Vb + l31 * 128 + dt * 4096 + ((kb * 32 + hi * 16) ^ x16));
        accO[dt] = mfma32(vfr, pfrag[kb], accO[dt]);
      }
    }

    __syncthreads();  // all waves done reading this tile
    if (kv + 64 < kv_hi) {
#pragma unroll
      for (int j = 0; j < 4; ++j) {
        int c = t + (j << 8);
        int row = c >> 4, ch = c & 15;
        gload_lds16(Kg_b + (size_t)(kv + 64 + row) * 128 + ((ch ^ (row & 7)) << 3),
                    Ks_lin + c * 8);
        int d = c >> 3, cv = c & 7;
        gload_lds16(Vg_b + (size_t)d * 2048 + (kv + 64) + ((cv ^ (d & 7)) << 3),
                    Vs_lin + c * 8);
      }
    }
    __syncthreads();  // DMA drained (compiler emits vmcnt(0) before s_barrier)
  }

  // epilogue: normalized partial O^T -> LDS -> coalesced store; (m,l) per q
  auto To = (unsigned short(*)[136])sm;
  const float invl = 1.f / l;
  const int qloc = wid * 32 + l31;
#pragma unroll
  for (int dt = 0; dt < 4; ++dt)
#pragma unroll
    for (int r = 0; r < 16; ++r) {
      int d = dt * 32 + (r & 3) + ((r >> 2) << 3) + hi * 4;
      To[d][qloc] = f2bf(accO[dt][r] * invl);
    }
  if (hi == 0) {
    float2 v; v.x = m; v.y = l;
    ML[bh * 2048 + qbase + qloc] = v;
  }
  __syncthreads();
  int dr = t >> 1;
  int off = (t & 1) << 6;
  unsigned short* dst = PO + base + (size_t)dr * 2048 + qbase + off;
#pragma unroll
  for (int j = 0; j < 8; ++j)
    ((uint4*)dst)[j] = *(const uint4*)&To[dr][off + j * 8];
}

// Combine weights per (bh,s) from the two KV-halves' (m,l).
__global__ __launch_bounds__(256) void attn_mweights(const float2* __restrict__ ml0,
                                                     const float2* __restrict__ ml1,
                                                     float2* __restrict__ w) {
  int idx = blockIdx.x * 256 + threadIdx.x;  // [0, 65536)
  float2 a = ml0[idx];
  float2 b = ml1[idx];
  float mm = fmaxf(a.x, b.x);
  float e0 = a.y * __expf((a.x - mm) * 0.3535533905932738f);
  float e1 = b.y * __expf((b.x - mm) * 0.3535533905932738f);
  float inv = 1.f / (e0 + e1);
  float2 o; o.x = e0 * inv; o.y = e1 * inv;
  w[idx] = o;
}

// O^T = w0*P0 + w1*P1 elementwise over [bh][d][s] (in-place onto P0 ok).
__global__ __launch_bounds__(256) void attn_merge(const unsigned short* __restrict__ P0,
                                                  const unsigned short* __restrict__ P1,
                                                  const float2* __restrict__ w,
                                                  unsigned short* __restrict__ O) {
  size_t idx = ((size_t)blockIdx.x * 256 + threadIdx.x) * 8;
  int s = (int)(idx & 2047);
  int bh = (int)(idx >> 18);
  uint4 a0 = *(const uint4*)(P0 + idx);
  uint4 a1 = *(const uint4*)(P1 + idx);
  const unsigned short* u0 = (const unsigned short*)&a0;
  const unsigned short* u1 = (const unsigned short*)&a1;
  const float4* wp = (const float4*)(w + ((size_t)bh << 11) + s);
  float2 ww[8];
#pragma unroll
  for (int j = 0; j < 4; ++j) *(float4*)&ww[j * 2] = wp[j];
  __align__(16) unsigned short o[8];
#pragma unroll
  for (int j = 0; j < 8; ++j)
    o[j] = f2bf(fmaf(ww[j].x, bf2f(u0[j]), ww[j].y * bf2f(u1[j])));
  *(uint4*)(O + idx) = *(const uint4*)o;
}

extern "C" void kernel_launch(void* const* d_in, const int* in_sizes, int n_in,
                              void* d_out, int out_size, void* d_ws, size_t ws_size,
                              hipStream_t stream) {
  const float* emb = (const float*)d_in[0];
  const float* W1  = (const float*)d_in[1];
  const float* W2  = (const float*)d_in[2];
  const float* W3  = (const float*)d_in[3];
  const float* Wo  = (const float*)d_in[4];
  float* out = (float*)d_out;

  const size_t NELEM = (size_t)8 * 1024 * 1024;  // bf16 elems per [B*S, P] buffer
  unsigned short* q     = (unsigned short*)d_ws;   // [0,16) MB
  unsigned short* k     = q + NELEM;               // [16,32)
  unsigned short* vn    = k + NELEM;               // [32,48); later P0 (merged oT)
  unsigned short* X     = vn + NELEM;              // [48,64): W123B -> vT -> WoB
  unsigned short* oT    = vn;                      // partial half-0 / merged O^T
  unsigned short* vT    = X;
  unsigned short* W123B = X;                       // 6 MB, dead before vT written
  unsigned short* WoB   = X;                       // 2 MB, written after flash
  unsigned short* embB  = (unsigned short*)d_out;  // 16 MB bf16 scratch in fp32 out
                                                   // buffer; dead after gemm_qkv
  // d_out scratch after gemm_qkv: P1 partial (16MB) + ml0/ml1 (0.5MB each) + w
  unsigned short* P1  = (unsigned short*)d_out;
  float2* ml0 = (float2*)((char*)d_out + (size_t)(16 << 20));
  float2* ml1 = (float2*)((char*)d_out + (size_t)(16 << 20) + (512 << 10));
  float2* wbf = (float2*)((char*)d_out + (size_t)(17 << 20));

  dim3 blk(256, 1, 1);
  convert_w3<<<dim3(1536), blk, 0, stream>>>(W1, W2, W3, W123B);
  convert_gen<<<dim3(4096), blk, 0, stream>>>(emb, embB);
  gemm_qkv<<<dim3(24, 64), blk, 0, stream>>>(embB, W123B, q, k, vn);
  transpose_v<<<dim3(32, 2, 32), blk, 0, stream>>>(vn, vT);
  flash_attn<<<dim3(1024, 1, 1), blk, 0, stream>>>(q, k, vT, oT, P1, ml0, ml1);
  attn_mweights<<<dim3(256), blk, 0, stream>>>(ml0, ml1, wbf);
  attn_merge<<<dim3(4096), blk, 0, stream>>>(oT, P1, wbf, oT);
  convert_gen<<<dim3(512), blk, 0, stream>>>(Wo, WoB);
  gemm_out<<<dim3(8, 64), blk, 0, stream>>>(oT, WoB, out);
}

// Round 3
// 372.383 us; speedup vs baseline: 1.1215x; 1.1215x over previous
//
#include <hip/hip_runtime.h>

typedef float f32x4 __attribute__((ext_vector_type(4)));
typedef float f32x16 __attribute__((ext_vector_type(16)));
typedef __bf16 bf16x8 __attribute__((ext_vector_type(8)));

__device__ __forceinline__ unsigned short f2bf(float f) {
  unsigned int u = __float_as_uint(f);
  u = (u + 0x7FFFu + ((u >> 16) & 1u)) >> 16;
  return (unsigned short)u;
}
__device__ __forceinline__ float bf2f(unsigned short u) {
  return __uint_as_float((unsigned int)u << 16);
}

__device__ __forceinline__ f32x4 mfma16(bf16x8 a, bf16x8 b, f32x4 c) {
  return __builtin_amdgcn_mfma_f32_16x16x32_bf16(a, b, c, 0, 0, 0);
}
__device__ __forceinline__ f32x16 mfma32(bf16x8 a, bf16x8 b, f32x16 c) {
  return __builtin_amdgcn_mfma_f32_32x32x16_bf16(a, b, c, 0, 0, 0);
}

// packed f32->bf16 pair (RNE), lo = a, hi = b
__device__ __forceinline__ unsigned int cvtpk_bf16(float a, float b) {
  unsigned int r;
  asm("v_cvt_pk_bf16_f32 %0, %1, %2" : "=v"(r) : "v"(a), "v"(b));
  return r;
}
// swap upper 32 lanes of a with lower 32 lanes of b (both outputs used)
__device__ __forceinline__ void pl32swap(unsigned int& a, unsigned int& b) {
  asm("v_permlane32_swap_b32 %0, %1" : "+v"(a), "+v"(b));
}

__device__ __forceinline__ void load8_bf16(const unsigned short* p, unsigned short* d) {
  *(uint4*)d = *(const uint4*)p;
}
__device__ __forceinline__ void load8_bf16(const float* p, unsigned short* d) {
  float4 a = *(const float4*)p;
  float4 b = *(const float4*)(p + 4);
  __align__(16) unsigned short t[8] = {f2bf(a.x), f2bf(a.y), f2bf(a.z), f2bf(a.w),
                                       f2bf(b.x), f2bf(b.y), f2bf(b.z), f2bf(b.w)};
  *(uint4*)d = *(uint4*)t;
}

// Async global->LDS 16B DMA. LDS dest must be wave-uniform base + lane*16.
__device__ __forceinline__ void gload_lds16(const unsigned short* g, unsigned short* l) {
  __builtin_amdgcn_global_load_lds(
      (const __attribute__((address_space(1))) void*)g,
      (__attribute__((address_space(3))) void*)l, 16, 0, 0);
}

// fp32 -> bf16, 8 elems/thread.
__global__ __launch_bounds__(256) void convert_gen(const float* __restrict__ src,
                                                   unsigned short* __restrict__ dst) {
  int idx = (blockIdx.x * 256 + threadIdx.x) * 8;
  __align__(16) unsigned short t[8];
  load8_bf16(src + idx, t);
  *(uint4*)(dst + idx) = *(uint4*)t;
}

// W1|W2|W3 (each 1M fp32) -> contiguous bf16. 1536 blocks.
__global__ __launch_bounds__(256) void convert_w3(const float* __restrict__ W1,
                                                  const float* __restrict__ W2,
                                                  const float* __restrict__ W3,
                                                  unsigned short* __restrict__ dst) {
  int i = blockIdx.x;
  int sel = i >> 9;
  const float* src = (sel == 0) ? W1 : (sel == 1) ? W2 : W3;
  int off = (i & 511) * 2048 + threadIdx.x * 8;
  __align__(16) unsigned short t[8];
  load8_bf16(src + off, t);
  *(uint4*)(dst + sel * 1048576 + off) = *(uint4*)t;
}

// Fused QKV projection, all-bf16, global_load_lds staging, unpadded LDS.
__global__ __launch_bounds__(256) void gemm_qkv(const unsigned short* __restrict__ A,
                                                const unsigned short* __restrict__ WB,
                                                unsigned short* __restrict__ q,
                                                unsigned short* __restrict__ k,
                                                unsigned short* __restrict__ v) {
  __shared__ __align__(16) unsigned short As[128][32];
  __shared__ __align__(16) unsigned short Bs[128][32];
  const int t = threadIdx.x;
  const int lane = t & 63;
  const int wid = t >> 6;
  const int quad = lane >> 4;
  const int l16 = lane & 15;
  const int wm = (wid >> 1) << 6;
  const int wn = (wid & 1) << 6;
  const int sel = blockIdx.x >> 3;
  const int nb = (blockIdx.x & 7) << 7;
  const int mbase = blockIdx.y * 128;
  const unsigned short* Bt = WB + sel * 1048576;
  unsigned short* C = (sel == 0) ? q : (sel == 1) ? k : v;

  f32x4 acc[4][4] = {};

  for (int k0 = 0; k0 < 1024; k0 += 32) {
#pragma unroll
    for (int i = 0; i < 2; ++i) {
      int c = t + (i << 8);
      int row = c >> 2;
      int col = (c & 3) << 3;
      gload_lds16(A + (size_t)(mbase + row) * 1024 + k0 + col, &As[row][col]);
      gload_lds16(Bt + (size_t)(nb + row) * 1024 + k0 + col, &Bs[row][col]);
    }
    __syncthreads();
    bf16x8 af[4], bfr[4];
#pragma unroll
    for (int mt = 0; mt < 4; ++mt)
      af[mt] = *(const bf16x8*)(&As[wm + mt * 16 + l16][quad * 8]);
#pragma unroll
    for (int nt = 0; nt < 4; ++nt)
      bfr[nt] = *(const bf16x8*)(&Bs[wn + nt * 16 + l16][quad * 8]);
#pragma unroll
    for (int mt = 0; mt < 4; ++mt)
#pragma unroll
      for (int nt = 0; nt < 4; ++nt)
        acc[mt][nt] = mfma16(af[mt], bfr[nt], acc[mt][nt]);
    __syncthreads();
  }

  const bool rope = (sel < 2);
#pragma unroll
  for (int mt = 0; mt < 4; ++mt) {
#pragma unroll
    for (int nt = 0; nt < 4; ++nt) {
#pragma unroll
      for (int r = 0; r < 4; ++r) {
        int row_g = mbase + wm + mt * 16 + quad * 4 + r;
        int col_g = nb + wn + nt * 16 + l16;
        float val = acc[mt][nt][r];
        if (rope) {  // interleaved RoPE; partner col = col^1 lives in lane^1
          float other = __shfl_xor(val, 1);
          int s = (((row_g & 2047) << 3) + (col_g >> 7)) & 2047;  // view-seq position
          int d = col_g & 127;
          float invf = __expf(-0.14391156f * (float)(d >> 1));  // ln(1e4)/64
          float ang = (float)s * invf;
          float sv, cv;
          __sincosf(ang, &sv, &cv);
          val = (d & 1) ? (val * cv + other * sv) : (val * cv - other * sv);
        }
        C[(size_t)row_g * 1024 + col_g] = f2bf(val);
      }
    }
  }
}

// Plain per-bh transpose: vT[bh][d][s] = v[bh][s][d].
__global__ __launch_bounds__(256) void transpose_v(const unsigned short* __restrict__ Vn,
                                                   unsigned short* __restrict__ VT) {
  __shared__ __align__(16) unsigned short tile[64][72];
  const int t = threadIdx.x;
  const int s0 = blockIdx.x * 64;
  const int d0 = blockIdx.y * 64;
  const int bh = blockIdx.z;
  const size_t base = (size_t)bh * (2048 * 128);
#pragma unroll
  for (int i = 0; i < 2; ++i) {
    int c = t + (i << 8);
    int sr = c >> 3;
    int dc = (c & 7) << 3;
    *(uint4*)(&tile[sr][dc]) = *(const uint4*)(Vn + base + (size_t)(s0 + sr) * 128 + d0 + dc);
  }
  __syncthreads();
#pragma unroll
  for (int i = 0; i < 2; ++i) {
    int c = t + (i << 8);
    int dr = c >> 3;
    int sc = (c & 7) << 3;
    __align__(16) unsigned short tmp[8];
#pragma unroll
    for (int j = 0; j < 8; ++j) tmp[j] = tile[sc + j][dr];
    *(uint4*)(VT + base + (size_t)(d0 + dr) * 2048 + s0 + sc) = *(uint4*)tmp;
  }
}

// Final projection: A rows remap RowLinear pre-shuffle onto oT[bh][d][s].
__global__ __launch_bounds__(256) void gemm_out(const unsigned short* __restrict__ OT,
                                                const unsigned short* __restrict__ Bt,
                                                float* __restrict__ C) {
  __shared__ __align__(16) char smem_raw[128 * 68 * 4];  // Ts epilogue needs 34816 B
  auto As = (unsigned short(*)[32])smem_raw;
  auto Bs = (unsigned short(*)[32])(smem_raw + 128 * 32 * 2);
  const int t = threadIdx.x;
  const int lane = t & 63;
  const int wid = t >> 6;
  const int quad = lane >> 4;
  const int l16 = lane & 15;
  const int wm = (wid >> 1) << 6;
  const int wn = (wid & 1) << 6;
  const int mbase = blockIdx.y * 128;
  const int nbase = blockIdx.x * 128;

  f32x4 acc[4][4] = {};

  for (int k0 = 0; k0 < 1024; k0 += 32) {
#pragma unroll
    for (int i = 0; i < 2; ++i) {
      int c = t + (i << 8);
      int row = c >> 2;
      int col = (c & 3) << 3;
      int R = mbase + row;
      int b = R >> 11;
      int ii = R & 2047;
      const unsigned short* src = OT + (size_t)(b * 8 + (ii >> 8)) * (128 * 2048) +
                                  (size_t)((ii >> 1) & 127) * 2048 + ((ii & 1) << 10) +
                                  k0 + col;
      gload_lds16(src, &As[row][col]);
      gload_lds16(Bt + (size_t)(nbase + row) * 1024 + k0 + col, &Bs[row][col]);
    }
    __syncthreads();
    bf16x8 af[4], bfr[4];
#pragma unroll
    for (int mt = 0; mt < 4; ++mt)
      af[mt] = *(const bf16x8*)(&As[wm + mt * 16 + l16][quad * 8]);
#pragma unroll
    for (int nt = 0; nt < 4; ++nt)
      bfr[nt] = *(const bf16x8*)(&Bs[wn + nt * 16 + l16][quad * 8]);
#pragma unroll
    for (int mt = 0; mt < 4; ++mt)
#pragma unroll
      for (int nt = 0; nt < 4; ++nt)
        acc[mt][nt] = mfma16(af[mt], bfr[nt], acc[mt][nt]);
    __syncthreads();
  }

  // out[b][s2][e2], s2 = (row&1)*1024 + col, e2 = (row&2047)>>1.
  float(*Ts)[68] = (float(*)[68])smem_raw;
  const int b = mbase >> 11;
  const int ebase = (mbase & 2047) >> 1;
#pragma unroll
  for (int p = 0; p < 2; ++p) {
    __syncthreads();
#pragma unroll
    for (int mt = 0; mt < 4; ++mt)
#pragma unroll
      for (int nt = 0; nt < 4; ++nt)
#pragma unroll
        for (int rr = p; rr < 4; rr += 2) {
          int col_local = wn + nt * 16 + l16;
          int row_local = wm + mt * 16 + quad * 4 + rr;
          Ts[col_local][row_local >> 1] = acc[mt][nt][rr];
        }
    __syncthreads();
    int srow = t >> 1;
    int e0 = (t & 1) << 5;
    float* dst = C + (size_t)b * 2097152 +
                 (size_t)(p * 1024 + nbase + srow) * 1024 + ebase + e0;
#pragma unroll
    for (int j = 0; j < 8; ++j)
      ((float4*)dst)[j] = *(const float4*)&Ts[srow][e0 + j * 4];
  }
}

// Flash attention [BH=32, S=2048, D=128]; split-KV (2 halves), BQ=128
// (4 waves x 32 q-cols), BKV=64. Swapped QK^T on 32x32 MFMA (S^T in regs,
// q = lane&31), in-register softmax, cvt_pk+permlane32 P-repack, PV as
// V^T x P^T -> O^T. K double-buffered (2x16KB) + V single (16KB), DMA'd via
// global_load_lds with pre-swizzled source; raw s_barrier + COUNTED vmcnt
// (never 0 in steady state) so K-DMA hides under compute. 3 blocks/CU.
__global__ __launch_bounds__(256, 3) void flash_attn(const unsigned short* __restrict__ Q,
                                                     const unsigned short* __restrict__ Kg,
                                                     const unsigned short* __restrict__ VTg,
                                                     unsigned short* __restrict__ PO0,
                                                     unsigned short* __restrict__ PO1,
                                                     float2* __restrict__ ML0,
                                                     float2* __restrict__ ML1) {
  __shared__ __align__(16) char sm[49152];  // K0 | K1 | V; epilogue To overlays [0,34816)
  const int t = threadIdx.x;
  const int lane = t & 63;
  const int wid = t >> 6;
  const int l31 = lane & 31;
  const int hi = lane >> 5;
  const int x16 = (l31 & 7) << 4;  // XOR swizzle key (byte units)
  const int i = blockIdx.x;        // [0,1024); i%32 -> bh (XCD-clustered)
  const int bh = (i & 7) + ((i >> 3) & 3) * 8;
  const int half = (i >> 5) & 1;
  const int qbase = (i >> 6) << 7;
  const int kv_lo = half << 10;
  const int kv_hi = kv_lo + 1024;
  const size_t base = (size_t)bh * (2048 * 128);
  const float scale = 0.3535533905932738f;  // 1/sqrt(H=8)

  unsigned short* PO = half ? PO1 : PO0;
  float2* ML = half ? ML1 : ML0;
  unsigned short* Vl = (unsigned short*)(sm + 32768);

  const unsigned short* Kg_b = Kg + base;
  const unsigned short* Vg_b = VTg + base;

  auto issueK = [&](int kvoff, int pbit) {
#pragma unroll
    for (int j = 0; j < 4; ++j) {
      int c = t + (j << 8);
      int row = c >> 4, ch = c & 15;
      gload_lds16(Kg_b + (size_t)(kvoff + row) * 128 + ((ch ^ (row & 7)) << 3),
                  (unsigned short*)(sm + (pbit << 14)) + c * 8);
    }
  };
  auto issueV = [&](int kvoff) {
#pragma unroll
    for (int j = 0; j < 4; ++j) {
      int c = t + (j << 8);
      int d = c >> 3, cv = c & 7;
      gload_lds16(Vg_b + (size_t)d * 2048 + kvoff + ((cv ^ (d & 7)) << 3), Vl + c * 8);
    }
  };

  // Q fragments (B-operand): j = q = l31, k-dim slice = hi*8 within each 16.
  bf16x8 qf[8];
  {
    const unsigned short* qp = Q + base + (size_t)(qbase + wid * 32 + l31) * 128 + hi * 8;
#pragma unroll
    for (int ks = 0; ks < 8; ++ks) qf[ks] = *(const bf16x8*)(qp + ks * 16);
  }

  f32x16 accO[4] = {};  // O^T: rows d, cols q = l31
  float m = -__builtin_inff();
  float l = 0.f;

  // prologue: DMA K0,V0; wait K0 (V0 may stay in flight)
  issueK(kv_lo, 0);
  issueV(kv_lo);
  asm volatile("s_waitcnt vmcnt(4)" ::: "memory");
  __builtin_amdgcn_sched_barrier(0);
  __builtin_amdgcn_s_barrier();
  __builtin_amdgcn_sched_barrier(0);

  int p = 0;
  for (int kv = kv_lo; kv < kv_hi; kv += 64) {
    const bool nxt = (kv + 64) < kv_hi;
    if (nxt) issueK(kv + 64, p ^ 1);  // prefetch K into other buffer (hidden)
    const char* Kb = sm + (p << 14);

    // QK^T swapped: S^T (rows k, cols q = l31)
    f32x16 s0 = {}, s1 = {};
#pragma unroll
    for (int ks = 0; ks < 8; ++ks) {
      int cb = (ks * 32 + hi * 16) ^ x16;
      bf16x8 k0 = *(const bf16x8*)(Kb + l31 * 256 + cb);
      bf16x8 k1 = *(const bf16x8*)(Kb + 8192 + l31 * 256 + cb);
      s0 = mfma32(k0, qf[ks], s0);
      s1 = mfma32(k1, qf[ks], s1);
    }

    // online softmax: per-lane row (q = l31); 8-temp folded trees
    float t8[8];
#pragma unroll
    for (int r = 0; r < 8; ++r)
      t8[r] = fmaxf(fmaxf(s0[r], s0[r + 8]), fmaxf(s1[r], s1[r + 8]));
#pragma unroll
    for (int d = 4; d > 0; d >>= 1)
#pragma unroll
      for (int r = 0; r < d; ++r) t8[r] = fmaxf(t8[r], t8[r + d]);
    float mx = fmaxf(t8[0], __shfl_xor(t8[0], 32));
    if (__any(mx > m + 16.f)) {  // defer-max: P bounded by e^(16*scale)=287
      float mnew = fmaxf(m, mx);
      float alpha = __expf((m - mnew) * scale);
      l *= alpha;
#pragma unroll
      for (int dt = 0; dt < 4; ++dt)
#pragma unroll
        for (int r = 0; r < 16; ++r) accO[dt][r] *= alpha;
      m = mnew;
    }
    float negms = -m * scale;
#pragma unroll
    for (int r = 0; r < 16; ++r) s0[r] = __expf(fmaf(s0[r], scale, negms));
#pragma unroll
    for (int r = 0; r < 16; ++r) s1[r] = __expf(fmaf(s1[r], scale, negms));
#pragma unroll
    for (int r = 0; r < 8; ++r)
      t8[r] = (s0[r] + s0[r + 8]) + (s1[r] + s1[r + 8]);
#pragma unroll
    for (int d = 4; d > 0; d >>= 1)
#pragma unroll
      for (int r = 0; r < d; ++r) t8[r] += t8[r + d];
    l += t8[0] + __shfl_xor(t8[0], 32);

    // repack P^T -> B-fragments: cvt_pk pairs + permlane32_swap
    bf16x8 pfrag[4];
#pragma unroll
    for (int kb = 0; kb < 4; ++kb) {
      const f32x16& S = (kb < 2) ? s0 : s1;
      const int b = (kb & 1) * 8;
      unsigned int a0 = cvtpk_bf16(S[b + 0], S[b + 1]);
      unsigned int a1 = cvtpk_bf16(S[b + 2], S[b + 3]);
      unsigned int a2 = cvtpk_bf16(S[b + 4], S[b + 5]);
      unsigned int a3 = cvtpk_bf16(S[b + 6], S[b + 7]);
      pl32swap(a0, a2);
      pl32swap(a1, a3);
      union { unsigned int u[4]; bf16x8 v; } pu;
      pu.u[0] = a0; pu.u[1] = a1; pu.u[2] = a2; pu.u[3] = a3;
      pfrag[kb] = pu.v;
    }

    // V_t arrived? (queue: [V_t(4), K'(4 if nxt)])
    if (nxt) { asm volatile("s_waitcnt vmcnt(4)" ::: "memory"); }
    else     { asm volatile("s_waitcnt vmcnt(0)" ::: "memory"); }
    __builtin_amdgcn_sched_barrier(0);
    __builtin_amdgcn_s_barrier();
    __builtin_amdgcn_sched_barrier(0);

    // PV: O^T[d][q] += V^T-frag (i=d) x P^T-frag (j=q)
#pragma unroll
    for (int dt = 0; dt < 4; ++dt) {
#pragma unroll
      for (int kb = 0; kb < 4; ++kb) {
        bf16x8 vfr = *(const bf16x8*)(sm + 32768 + l31 * 128 + dt * 4096 +
                                      ((kb * 32 + hi * 16) ^ x16));
        accO[dt] = mfma32(vfr, pfrag[kb], accO[dt]);
      }
    }

    // all waves done reading V_t (and K_t)
    __builtin_amdgcn_sched_barrier(0);
    __builtin_amdgcn_s_barrier();
    __builtin_amdgcn_sched_barrier(0);

    if (nxt) {
      issueV(kv + 64);  // overwrite V buffer (safe: post-barrier)
      asm volatile("s_waitcnt vmcnt(4)" ::: "memory");  // K_{t+1} arrived
      __builtin_amdgcn_sched_barrier(0);
      __builtin_amdgcn_s_barrier();
      __builtin_amdgcn_sched_barrier(0);
    }
    p ^= 1;
  }

  // epilogue: normalized partial O^T -> LDS -> coalesced store; (m,l) per q
  auto To = (unsigned short(*)[136])sm;
  const float invl = 1.f / l;
  const int qloc = wid * 32 + l31;
#pragma unroll
  for (int dt = 0; dt < 4; ++dt)
#pragma unroll
    for (int r = 0; r < 16; ++r) {
      int d = dt * 32 + (r & 3) + ((r >> 2) << 3) + hi * 4;
      To[d][qloc] = f2bf(accO[dt][r] * invl);
    }
  if (hi == 0) {
    float2 v; v.x = m; v.y = l;
    ML[bh * 2048 + qbase + qloc] = v;
  }
  __syncthreads();
  int dr = t >> 1;
  int off = (t & 1) << 6;
  unsigned short* dst = PO + base + (size_t)dr * 2048 + qbase + off;
#pragma unroll
  for (int j = 0; j < 8; ++j)
    ((uint4*)dst)[j] = *(const uint4*)&To[dr][off + j * 8];
}

// Combine weights per (bh,s) from the two KV-halves' (m,l).
__global__ __launch_bounds__(256) void attn_mweights(const float2* __restrict__ ml0,
                                                     const float2* __restrict__ ml1,
                                                     float2* __restrict__ w) {
  int idx = blockIdx.x * 256 + threadIdx.x;  // [0, 65536)
  float2 a = ml0[idx];
  float2 b = ml1[idx];
  float mm = fmaxf(a.x, b.x);
  float e0 = a.y * __expf((a.x - mm) * 0.3535533905932738f);
  float e1 = b.y * __expf((b.x - mm) * 0.3535533905932738f);
  float inv = 1.f / (e0 + e1);
  float2 o; o.x = e0 * inv; o.y = e1 * inv;
  w[idx] = o;
}

// O^T = w0*P0 + w1*P1 elementwise over [bh][d][s] (in-place onto P0 ok).
__global__ __launch_bounds__(256) void attn_merge(const unsigned short* __restrict__ P0,
                                                  const unsigned short* __restrict__ P1,
                                                  const float2* __restrict__ w,
                                                  unsigned short* __restrict__ O) {
  size_t idx = ((size_t)blockIdx.x * 256 + threadIdx.x) * 8;
  int s = (int)(idx & 2047);
  int bh = (int)(idx >> 18);
  uint4 a0 = *(const uint4*)(P0 + idx);
  uint4 a1 = *(const uint4*)(P1 + idx);
  const unsigned short* u0 = (const unsigned short*)&a0;
  const unsigned short* u1 = (const unsigned short*)&a1;
  const float4* wp = (const float4*)(w + ((size_t)bh << 11) + s);
  float2 ww[8];
#pragma unroll
  for (int j = 0; j < 4; ++j) *(float4*)&ww[j * 2] = wp[j];
  __align__(16) unsigned short o[8];
#pragma unroll
  for (int j = 0; j < 8; ++j)
    o[j] = f2bf(fmaf(ww[j].x, bf2f(u0[j]), ww[j].y * bf2f(u1[j])));
  *(uint4*)(O + idx) = *(const uint4*)o;
}

extern "C" void kernel_launch(void* const* d_in, const int* in_sizes, int n_in,
                              void* d_out, int out_size, void* d_ws, size_t ws_size,
                              hipStream_t stream) {
  const float* emb = (const float*)d_in[0];
  const float* W1  = (const float*)d_in[1];
  const float* W2  = (const float*)d_in[2];
  const float* W3  = (const float*)d_in[3];
  const float* Wo  = (const float*)d_in[4];
  float* out = (float*)d_out;

  const size_t NELEM = (size_t)8 * 1024 * 1024;  // bf16 elems per [B*S, P] buffer
  unsigned short* q     = (unsigned short*)d_ws;   // [0,16) MB
  unsigned short* k     = q + NELEM;               // [16,32)
  unsigned short* vn    = k + NELEM;               // [32,48); later P0 (merged oT)
  unsigned short* X     = vn + NELEM;              // [48,64): W123B -> vT -> WoB
  unsigned short* oT    = vn;                      // partial half-0 / merged O^T
  unsigned short* vT    = X;
  unsigned short* W123B = X;                       // 6 MB, dead before vT written
  unsigned short* WoB   = X;                       // 2 MB, written after flash
  unsigned short* embB  = (unsigned short*)d_out;  // 16 MB bf16 scratch in fp32 out
                                                   // buffer; dead after gemm_qkv
  // d_out scratch after gemm_qkv: P1 partial (16MB) + ml0/ml1 (0.5MB each) + w
  unsigned short* P1  = (unsigned short*)d_out;
  float2* ml0 = (float2*)((char*)d_out + (size_t)(16 << 20));
  float2* ml1 = (float2*)((char*)d_out + (size_t)(16 << 20) + (512 << 10));
  float2* wbf = (float2*)((char*)d_out + (size_t)(17 << 20));

  dim3 blk(256, 1, 1);
  convert_w3<<<dim3(1536), blk, 0, stream>>>(W1, W2, W3, W123B);
  convert_gen<<<dim3(4096), blk, 0, stream>>>(emb, embB);
  gemm_qkv<<<dim3(24, 64), blk, 0, stream>>>(embB, W123B, q, k, vn);
  transpose_v<<<dim3(32, 2, 32), blk, 0, stream>>>(vn, vT);
  flash_attn<<<dim3(1024, 1, 1), blk, 0, stream>>>(q, k, vT, oT, P1, ml0, ml1);
  attn_mweights<<<dim3(256), blk, 0, stream>>>(ml0, ml1, wbf);
  attn_merge<<<dim3(4096), blk, 0, stream>>>(oT, P1, wbf, oT);
  convert_gen<<<dim3(512), blk, 0, stream>>>(Wo, WoB);
  gemm_out<<<dim3(8, 64), blk, 0, stream>>>(oT, WoB, out);
}

// Round 4
// 318.674 us; speedup vs baseline: 1.3106x; 1.1685x over previous
//
#include <hip/hip_runtime.h>

typedef float f32x4 __attribute__((ext_vector_type(4)));
typedef float f32x16 __attribute__((ext_vector_type(16)));
typedef __bf16 bf16x8 __attribute__((ext_vector_type(8)));

__device__ __forceinline__ unsigned short f2bf(float f) {
  unsigned int u = __float_as_uint(f);
  u = (u + 0x7FFFu + ((u >> 16) & 1u)) >> 16;
  return (unsigned short)u;
}
__device__ __forceinline__ float bf2f(unsigned short u) {
  return __uint_as_float((unsigned int)u << 16);
}

__device__ __forceinline__ f32x4 mfma16(bf16x8 a, bf16x8 b, f32x4 c) {
  return __builtin_amdgcn_mfma_f32_16x16x32_bf16(a, b, c, 0, 0, 0);
}
__device__ __forceinline__ f32x16 mfma32(bf16x8 a, bf16x8 b, f32x16 c) {
  return __builtin_amdgcn_mfma_f32_32x32x16_bf16(a, b, c, 0, 0, 0);
}

// packed f32->bf16 pair (RNE), lo = a, hi = b
__device__ __forceinline__ unsigned int cvtpk_bf16(float a, float b) {
  unsigned int r;
  asm("v_cvt_pk_bf16_f32 %0, %1, %2" : "=v"(r) : "v"(a), "v"(b));
  return r;
}
// swap upper 32 lanes of a with lower 32 lanes of b (both outputs used)
__device__ __forceinline__ void pl32swap(unsigned int& a, unsigned int& b) {
  asm("v_permlane32_swap_b32 %0, %1" : "+v"(a), "+v"(b));
}

__device__ __forceinline__ void load8_bf16(const unsigned short* p, unsigned short* d) {
  *(uint4*)d = *(const uint4*)p;
}
__device__ __forceinline__ void load8_bf16(const float* p, unsigned short* d) {
  float4 a = *(const float4*)p;
  float4 b = *(const float4*)(p + 4);
  __align__(16) unsigned short t[8] = {f2bf(a.x), f2bf(a.y), f2bf(a.z), f2bf(a.w),
                                       f2bf(b.x), f2bf(b.y), f2bf(b.z), f2bf(b.w)};
  *(uint4*)d = *(uint4*)t;
}

// Async global->LDS 16B DMA. LDS dest must be wave-uniform base + lane*16.
__device__ __forceinline__ void gload_lds16(const unsigned short* g, unsigned short* l) {
  __builtin_amdgcn_global_load_lds(
      (const __attribute__((address_space(1))) void*)g,
      (__attribute__((address_space(3))) void*)l, 16, 0, 0);
}

__device__ __forceinline__ void drain_barrier() {
  asm volatile("s_waitcnt vmcnt(0)" ::: "memory");
  __builtin_amdgcn_sched_barrier(0);
  __builtin_amdgcn_s_barrier();
  __builtin_amdgcn_sched_barrier(0);
}

// fp32 -> bf16, 8 elems/thread.
__global__ __launch_bounds__(256) void convert_gen(const float* __restrict__ src,
                                                   unsigned short* __restrict__ dst) {
  int idx = (blockIdx.x * 256 + threadIdx.x) * 8;
  __align__(16) unsigned short t[8];
  load8_bf16(src + idx, t);
  *(uint4*)(dst + idx) = *(uint4*)t;
}

// W1|W2|W3 (each 1M fp32) -> contiguous bf16. 1536 blocks.
__global__ __launch_bounds__(256) void convert_w3(const float* __restrict__ W1,
                                                  const float* __restrict__ W2,
                                                  const float* __restrict__ W3,
                                                  unsigned short* __restrict__ dst) {
  int i = blockIdx.x;
  int sel = i >> 9;
  const float* src = (sel == 0) ? W1 : (sel == 1) ? W2 : W3;
  int off = (i & 511) * 2048 + threadIdx.x * 8;
  __align__(16) unsigned short t[8];
  load8_bf16(src + off, t);
  *(uint4*)(dst + sel * 1048576 + off) = *(uint4*)t;
}

// Fused QKV projection, all-bf16, global_load_lds staging, LDS double-buffered:
// issue DMA for K-step k0+32 at top of step k0, drain AFTER compute (one raw
// barrier per step; DMA latency hides under the 16-MFMA body).
__global__ __launch_bounds__(256) void gemm_qkv(const unsigned short* __restrict__ A,
                                                const unsigned short* __restrict__ WB,
                                                unsigned short* __restrict__ q,
                                                unsigned short* __restrict__ k,
                                                unsigned short* __restrict__ v) {
  __shared__ __align__(16) unsigned short As[2][128][32];
  __shared__ __align__(16) unsigned short Bs[2][128][32];
  const int t = threadIdx.x;
  const int lane = t & 63;
  const int wid = t >> 6;
  const int quad = lane >> 4;
  const int l16 = lane & 15;
  const int wm = (wid >> 1) << 6;
  const int wn = (wid & 1) << 6;
  const int sel = blockIdx.x >> 3;
  const int nb = (blockIdx.x & 7) << 7;
  const int mbase = blockIdx.y * 128;
  const unsigned short* Bt = WB + sel * 1048576;
  unsigned short* C = (sel == 0) ? q : (sel == 1) ? k : v;

  f32x4 acc[4][4] = {};

  auto stage = [&](int k0, int p) {
#pragma unroll
    for (int i = 0; i < 2; ++i) {
      int c = t + (i << 8);
      int row = c >> 2;
      int col = (c & 3) << 3;
      gload_lds16(A + (size_t)(mbase + row) * 1024 + k0 + col, &As[p][row][col]);
      gload_lds16(Bt + (size_t)(nb + row) * 1024 + k0 + col, &Bs[p][row][col]);
    }
  };

  stage(0, 0);
  drain_barrier();

  for (int k0 = 0; k0 < 1024; k0 += 32) {
    const int p = (k0 >> 5) & 1;
    if (k0 + 32 < 1024) stage(k0 + 32, p ^ 1);
    bf16x8 af[4], bfr[4];
#pragma unroll
    for (int mt = 0; mt < 4; ++mt)
      af[mt] = *(const bf16x8*)(&As[p][wm + mt * 16 + l16][quad * 8]);
#pragma unroll
    for (int nt = 0; nt < 4; ++nt)
      bfr[nt] = *(const bf16x8*)(&Bs[p][wn + nt * 16 + l16][quad * 8]);
#pragma unroll
    for (int mt = 0; mt < 4; ++mt)
#pragma unroll
      for (int nt = 0; nt < 4; ++nt)
        acc[mt][nt] = mfma16(af[mt], bfr[nt], acc[mt][nt]);
    drain_barrier();
  }

  const bool rope = (sel < 2);
#pragma unroll
  for (int mt = 0; mt < 4; ++mt) {
#pragma unroll
    for (int nt = 0; nt < 4; ++nt) {
#pragma unroll
      for (int r = 0; r < 4; ++r) {
        int row_g = mbase + wm + mt * 16 + quad * 4 + r;
        int col_g = nb + wn + nt * 16 + l16;
        float val = acc[mt][nt][r];
        if (rope) {  // interleaved RoPE; partner col = col^1 lives in lane^1
          float other = __shfl_xor(val, 1);
          int s = (((row_g & 2047) << 3) + (col_g >> 7)) & 2047;  // view-seq position
          int d = col_g & 127;
          float invf = __expf(-0.14391156f * (float)(d >> 1));  // ln(1e4)/64
          float ang = (float)s * invf;
          float sv, cv;
          __sincosf(ang, &sv, &cv);
          val = (d & 1) ? (val * cv + other * sv) : (val * cv - other * sv);
        }
        C[(size_t)row_g * 1024 + col_g] = f2bf(val);
      }
    }
  }
}

// Plain per-bh transpose: vT[bh][d][s] = v[bh][s][d].
__global__ __launch_bounds__(256) void transpose_v(const unsigned short* __restrict__ Vn,
                                                   unsigned short* __restrict__ VT) {
  __shared__ __align__(16) unsigned short tile[64][72];
  const int t = threadIdx.x;
  const int s0 = blockIdx.x * 64;
  const int d0 = blockIdx.y * 64;
  const int bh = blockIdx.z;
  const size_t base = (size_t)bh * (2048 * 128);
#pragma unroll
  for (int i = 0; i < 2; ++i) {
    int c = t + (i << 8);
    int sr = c >> 3;
    int dc = (c & 7) << 3;
    *(uint4*)(&tile[sr][dc]) = *(const uint4*)(Vn + base + (size_t)(s0 + sr) * 128 + d0 + dc);
  }
  __syncthreads();
#pragma unroll
  for (int i = 0; i < 2; ++i) {
    int c = t + (i << 8);
    int dr = c >> 3;
    int sc = (c & 7) << 3;
    __align__(16) unsigned short tmp[8];
#pragma unroll
    for (int j = 0; j < 8; ++j) tmp[j] = tile[sc + j][dr];
    *(uint4*)(VT + base + (size_t)(d0 + dr) * 2048 + s0 + sc) = *(uint4*)tmp;
  }
}

// Final projection: A rows remap RowLinear pre-shuffle onto oT[bh][d][s];
// LDS double-buffered, issue-early/drain-late, one barrier per K-step.
__global__ __launch_bounds__(256) void gemm_out(const unsigned short* __restrict__ OT,
                                                const unsigned short* __restrict__ Bt,
                                                float* __restrict__ C) {
  __shared__ __align__(16) char smem_raw[128 * 68 * 4];  // dbuf 32KB; Ts needs 34816 B
  const int t = threadIdx.x;
  const int lane = t & 63;
  const int wid = t >> 6;
  const int quad = lane >> 4;
  const int l16 = lane & 15;
  const int wm = (wid >> 1) << 6;
  const int wn = (wid & 1) << 6;
  const int mbase = blockIdx.y * 128;
  const int nbase = blockIdx.x * 128;

  f32x4 acc[4][4] = {};

  auto stage = [&](int k0, int p) {
    auto As = (unsigned short(*)[32])(smem_raw + p * 16384);
    auto Bs = (unsigned short(*)[32])(smem_raw + p * 16384 + 8192);
#pragma unroll
    for (int i = 0; i < 2; ++i) {
      int c = t + (i << 8);
      int row = c >> 2;
      int col = (c & 3) << 3;
      int R = mbase + row;
      int b = R >> 11;
      int ii = R & 2047;
      const unsigned short* src = OT + (size_t)(b * 8 + (ii >> 8)) * (128 * 2048) +
                                  (size_t)((ii >> 1) & 127) * 2048 + ((ii & 1) << 10) +
                                  k0 + col;
      gload_lds16(src, &As[row][col]);
      gload_lds16(Bt + (size_t)(nbase + row) * 1024 + k0 + col, &Bs[row][col]);
    }
  };

  stage(0, 0);
  drain_barrier();

  for (int k0 = 0; k0 < 1024; k0 += 32) {
    const int p = (k0 >> 5) & 1;
    if (k0 + 32 < 1024) stage(k0 + 32, p ^ 1);
    auto As = (unsigned short(*)[32])(smem_raw + p * 16384);
    auto Bs = (unsigned short(*)[32])(smem_raw + p * 16384 + 8192);
    bf16x8 af[4], bfr[4];
#pragma unroll
    for (int mt = 0; mt < 4; ++mt)
      af[mt] = *(const bf16x8*)(&As[wm + mt * 16 + l16][quad * 8]);
#pragma unroll
    for (int nt = 0; nt < 4; ++nt)
      bfr[nt] = *(const bf16x8*)(&Bs[wn + nt * 16 + l16][quad * 8]);
#pragma unroll
    for (int mt = 0; mt < 4; ++mt)
#pragma unroll
      for (int nt = 0; nt < 4; ++nt)
        acc[mt][nt] = mfma16(af[mt], bfr[nt], acc[mt][nt]);
    drain_barrier();
  }

  // out[b][s2][e2], s2 = (row&1)*1024 + col, e2 = (row&2047)>>1.
  float(*Ts)[68] = (float(*)[68])smem_raw;
  const int b = mbase >> 11;
  const int ebase = (mbase & 2047) >> 1;
#pragma unroll
  for (int p = 0; p < 2; ++p) {
    __syncthreads();
#pragma unroll
    for (int mt = 0; mt < 4; ++mt)
#pragma unroll
      for (int nt = 0; nt < 4; ++nt)
#pragma unroll
        for (int rr = p; rr < 4; rr += 2) {
          int col_local = wn + nt * 16 + l16;
          int row_local = wm + mt * 16 + quad * 4 + rr;
          Ts[col_local][row_local >> 1] = acc[mt][nt][rr];
        }
    __syncthreads();
    int srow = t >> 1;
    int e0 = (t & 1) << 5;
    float* dst = C + (size_t)b * 2097152 +
                 (size_t)(p * 1024 + nbase + srow) * 1024 + ebase + e0;
#pragma unroll
    for (int j = 0; j < 8; ++j)
      ((float4*)dst)[j] = *(const float4*)&Ts[srow][e0 + j * 4];
  }
}

// Flash attention [BH=32, S=2048, D=128]; full KV per block, BQ=128
// (4 waves x 32 q-cols), BKV=64. Swapped QK^T on 32x32 MFMA (S^T in regs,
// q = lane&31), in-register softmax, cvt_pk+permlane32 P-repack, PV as
// V^T x P^T -> O^T. K AND V double-buffered (64KB LDS), staged via
// global_load_lds with pre-swizzled source: issue tile t+1 at top of tile t,
// drain + ONE raw barrier after compute. Grid 512 = exactly 2 blocks/CU.
__global__ __launch_bounds__(256, 2) void flash_attn(const unsigned short* __restrict__ Q,
                                                     const unsigned short* __restrict__ Kg,
                                                     const unsigned short* __restrict__ VTg,
                                                     unsigned short* __restrict__ OT) {
  __shared__ __align__(16) char sm[65536];  // K0|K1|V0|V1 16KB each; epilogue overlays
  const int t = threadIdx.x;
  const int lane = t & 63;
  const int wid = t >> 6;
  const int l31 = lane & 31;
  const int hi = lane >> 5;
  const int x16 = (l31 & 7) << 4;  // XOR swizzle key (byte units)
  const int i = blockIdx.x;        // [0,512); XCD-aware swizzle
  const int bh = (i & 7) + ((i >> 3) & 3) * 8;
  const int qbase = (i >> 5) << 7;
  const size_t base = (size_t)bh * (2048 * 128);
  const float scale = 0.3535533905932738f;  // 1/sqrt(H=8)

  const unsigned short* Kg_b = Kg + base;
  const unsigned short* Vg_b = VTg + base;

  auto issueKV = [&](int kvoff, int pbit) {
    unsigned short* Kl = (unsigned short*)(sm + (pbit << 14));
    unsigned short* Vl = (unsigned short*)(sm + 32768 + (pbit << 14));
#pragma unroll
    for (int j = 0; j < 4; ++j) {
      int c = t + (j << 8);
      int row = c >> 4, ch = c & 15;
      gload_lds16(Kg_b + (size_t)(kvoff + row) * 128 + ((ch ^ (row & 7)) << 3),
                  Kl + c * 8);
      int d = c >> 3, cv = c & 7;
      gload_lds16(Vg_b + (size_t)d * 2048 + kvoff + ((cv ^ (d & 7)) << 3), Vl + c * 8);
    }
  };

  // Q fragments (B-operand): j = q = l31, k-dim slice = hi*8 within each 16.
  bf16x8 qf[8];
  {
    const unsigned short* qp = Q + base + (size_t)(qbase + wid * 32 + l31) * 128 + hi * 8;
#pragma unroll
    for (int ks = 0; ks < 8; ++ks) qf[ks] = *(const bf16x8*)(qp + ks * 16);
  }

  f32x16 accO[4] = {};  // O^T: rows d, cols q = l31
  float m = -__builtin_inff();
  float l = 0.f;

  issueKV(0, 0);
  drain_barrier();

  for (int kv = 0; kv < 2048; kv += 64) {
    const int p = (kv >> 6) & 1;
    if (kv + 64 < 2048) issueKV(kv + 64, p ^ 1);  // prefetch next tile (hidden)
    const char* Kb = sm + (p << 14);
    const char* Vb = sm + 32768 + (p << 14);

    // QK^T swapped: S^T (rows k, cols q = l31)
    f32x16 s0 = {}, s1 = {};
#pragma unroll
    for (int ks = 0; ks < 8; ++ks) {
      int cb = (ks * 32 + hi * 16) ^ x16;
      bf16x8 k0 = *(const bf16x8*)(Kb + l31 * 256 + cb);
      bf16x8 k1 = *(const bf16x8*)(Kb + 8192 + l31 * 256 + cb);
      s0 = mfma32(k0, qf[ks], s0);
      s1 = mfma32(k1, qf[ks], s1);
    }

    // online softmax: per-lane row (q = l31); 8-temp folded trees
    float t8[8];
#pragma unroll
    for (int r = 0; r < 8; ++r)
      t8[r] = fmaxf(fmaxf(s0[r], s0[r + 8]), fmaxf(s1[r], s1[r + 8]));
#pragma unroll
    for (int d = 4; d > 0; d >>= 1)
#pragma unroll
      for (int r = 0; r < d; ++r) t8[r] = fmaxf(t8[r], t8[r + d]);
    float mx = fmaxf(t8[0], __shfl_xor(t8[0], 32));
    if (__any(mx > m + 16.f)) {  // defer-max: P bounded by e^(16*scale)=287
      float mnew = fmaxf(m, mx);
      float alpha = __expf((m - mnew) * scale);
      l *= alpha;
#pragma unroll
      for (int dt = 0; dt < 4; ++dt)
#pragma unroll
        for (int r = 0; r < 16; ++r) accO[dt][r] *= alpha;
      m = mnew;
    }
    float negms = -m * scale;
#pragma unroll
    for (int r = 0; r < 16; ++r) s0[r] = __expf(fmaf(s0[r], scale, negms));
#pragma unroll
    for (int r = 0; r < 16; ++r) s1[r] = __expf(fmaf(s1[r], scale, negms));
#pragma unroll
    for (int r = 0; r < 8; ++r)
      t8[r] = (s0[r] + s0[r + 8]) + (s1[r] + s1[r + 8]);
#pragma unroll
    for (int d = 4; d > 0; d >>= 1)
#pragma unroll
      for (int r = 0; r < d; ++r) t8[r] += t8[r + d];
    l += t8[0] + __shfl_xor(t8[0], 32);

    // repack P^T -> B-fragments: cvt_pk pairs + permlane32_swap
    bf16x8 pfrag[4];
#pragma unroll
    for (int kb = 0; kb < 4; ++kb) {
      const f32x16& S = (kb < 2) ? s0 : s1;
      const int b = (kb & 1) * 8;
      unsigned int a0 = cvtpk_bf16(S[b + 0], S[b + 1]);
      unsigned int a1 = cvtpk_bf16(S[b + 2], S[b + 3]);
      unsigned int a2 = cvtpk_bf16(S[b + 4], S[b + 5]);
      unsigned int a3 = cvtpk_bf16(S[b + 6], S[b + 7]);
      pl32swap(a0, a2);
      pl32swap(a1, a3);
      union { unsigned int u[4]; bf16x8 v; } pu;
      pu.u[0] = a0; pu.u[1] = a1; pu.u[2] = a2; pu.u[3] = a3;
      pfrag[kb] = pu.v;
    }

    // PV: O^T[d][q] += V^T-frag (i=d) x P^T-frag (j=q)
#pragma unroll
    for (int dt = 0; dt < 4; ++dt) {
#pragma unroll
      for (int kb = 0; kb < 4; ++kb) {
        bf16x8 vfr = *(const bf16x8*)(Vb + l31 * 128 + dt * 4096 +
                                      ((kb * 32 + hi * 16) ^ x16));
        accO[dt] = mfma32(vfr, pfrag[kb], accO[dt]);
      }
    }

    // my prefetch DMAs landed long ago (hidden under compute); after this
    // barrier every wave's DMAs for tile t+1 are complete.
    drain_barrier();
  }

  // epilogue: accO is already O^T; normalize and stage to LDS for coalesced store
  auto To = (unsigned short(*)[136])sm;
  const float invl = 1.f / l;
  const int qloc = wid * 32 + l31;
#pragma unroll
  for (int dt = 0; dt < 4; ++dt)
#pragma unroll
    for (int r = 0; r < 16; ++r) {
      int d = dt * 32 + (r & 3) + ((r >> 2) << 3) + hi * 4;
      To[d][qloc] = f2bf(accO[dt][r] * invl);
    }
  __syncthreads();
  int dr = t >> 1;
  int off = (t & 1) << 6;
  unsigned short* dst = OT + base + (size_t)dr * 2048 + qbase + off;
#pragma unroll
  for (int j = 0; j < 8; ++j)
    ((uint4*)dst)[j] = *(const uint4*)&To[dr][off + j * 8];
}

extern "C" void kernel_launch(void* const* d_in, const int* in_sizes, int n_in,
                              void* d_out, int out_size, void* d_ws, size_t ws_size,
                              hipStream_t stream) {
  const float* emb = (const float*)d_in[0];
  const float* W1  = (const float*)d_in[1];
  const float* W2  = (const float*)d_in[2];
  const float* W3  = (const float*)d_in[3];
  const float* Wo  = (const float*)d_in[4];
  float* out = (float*)d_out;

  const size_t NELEM = (size_t)8 * 1024 * 1024;  // bf16 elems per [B*S, P] buffer
  unsigned short* q     = (unsigned short*)d_ws;   // [0,16) MB
  unsigned short* k     = q + NELEM;               // [16,32)
  unsigned short* vn    = k + NELEM;               // [32,48); later oT
  unsigned short* X     = vn + NELEM;              // [48,64): W123B -> vT -> WoB
  unsigned short* oT    = vn;
  unsigned short* vT    = X;
  unsigned short* W123B = X;                       // 6 MB, dead before vT written
  unsigned short* WoB   = X;                       // 2 MB, written after flash
  unsigned short* embB  = (unsigned short*)d_out;  // 16 MB bf16 scratch in the 32 MB
                                                   // fp32 out buffer; overwritten by gemm_out

  dim3 blk(256, 1, 1);
  convert_w3<<<dim3(1536), blk, 0, stream>>>(W1, W2, W3, W123B);
  convert_gen<<<dim3(4096), blk, 0, stream>>>(emb, embB);
  gemm_qkv<<<dim3(24, 64), blk, 0, stream>>>(embB, W123B, q, k, vn);
  transpose_v<<<dim3(32, 2, 32), blk, 0, stream>>>(vn, vT);
  flash_attn<<<dim3(512, 1, 1), blk, 0, stream>>>(q, k, vT, oT);
  convert_gen<<<dim3(512), blk, 0, stream>>>(Wo, WoB);
  gemm_out<<<dim3(8, 64), blk, 0, stream>>>(oT, WoB, out);
}